// Round 9
// baseline (237.360 us; speedup 1.0000x reference)
//
#include <hip/hip_runtime.h>
#include <hip/hip_bf16.h>

typedef __bf16 bf16x8 __attribute__((ext_vector_type(8)));
typedef float f32x4 __attribute__((ext_vector_type(4)));
typedef __attribute__((address_space(3))) void lds_void_t;
typedef __attribute__((address_space(1))) void gbl_void_t;

#define LRELU(x) ((x) >= 0.f ? (x) : 0.2f * (x))

__device__ __forceinline__ void gload16(void* lds_uniform, const void* gsrc) {
    __builtin_amdgcn_global_load_lds((const gbl_void_t*)gsrc, (lds_void_t*)lds_uniform,
                                     16, 0, 0);
}

__device__ __forceinline__ unsigned short f2u(float f) {
    __hip_bfloat16 h = __float2bfloat16(f);
    return reinterpret_cast<unsigned short&>(h);
}

// ---------------- f32 -> bf16 convert (vector4) ----------------------------
__global__ void cvt_f32_bf16(const float* __restrict__ in,
                             __hip_bfloat16* __restrict__ out, int n4) {
    int stride = gridDim.x * blockDim.x;
    for (int i = blockIdx.x * blockDim.x + threadIdx.x; i < n4; i += stride) {
        float4 v = reinterpret_cast<const float4*>(in)[i];
        ushort4 o;
        o.x = f2u(v.x); o.y = f2u(v.y); o.z = f2u(v.z); o.w = f2u(v.w);
        reinterpret_cast<ushort4*>(out)[i] = o;
    }
}

// ============ 256x256 8-phase GEMM with READ-AHEAD (counted lgkm) ==========
// Same geometry/ledger skeleton as R8 (2 bufs x 4 regions x 8192 el = 128 KB,
// BK=64, 2 tiles/iter, 8 phases). NEW: phase p's MFMA region issues phase
// p+1's ds_reads into the operand set NOT used by MFMA_p (afA/afB and bL/bH
// ping-pong naturally); NO lgkmcnt(0) drain -- reads are compiler-tracked, so
// the auto-inserted waitcnt is COUNTED (MFMA_p waits only its own phase-old
// operands; in-flight reads for p+1 hide under MFMA_p). Only bL at P1/P5 is
// read just-in-time (its register is in use at P4/P8 -- no spare VGPRs).
// Barriers: 1 per phase + mid-bars after the vmcnt(4) publishes at P4/P8.
// Ledger (re-derived for read-ahead):
//  RAW: reads of bufX issue only after a {vmcnt + barrier} pair that proves
//    ALL waves' stages of bufX landed (P4 publishes buf1, P8 publishes buf0;
//    per-wave vmcnt + barrier => block-wide). Last iter: vmcnt(0) (the (4)
//    would be vacuous with no new stages).
//  WAR: STG_p (issued right after bar_{p-1}) targets a region whose LDS
//    reads were consumed by MFMA_q (q<=p-1) via auto-lgkm before bar_q; all
//    waves passed bar_{p-1}>=bar_q => reads complete block-wide. Checked for
//    all 8 stages (tightest: P7's stage vs bH' consumed at MFMA_P6).
//  WAW: each region staged once per iter; vmcnt in-order drains older DMA.
// MODE 1: out = bf16(lrelu(bn(A@B^T)) + xq) ; MODE 2: out = bf16(lrelu(bn))
// ===========================================================================

#define MMQ(AF, BF, IH, JH)                                                   \
    {                                                                         \
        _Pragma("unroll") for (int r = 0; r < 4; ++r) {                       \
            _Pragma("unroll") for (int c = 0; c < 2; ++c) {                   \
                _Pragma("unroll") for (int s = 0; s < 2; ++s) {               \
                    acc[(IH) * 4 + r][(JH) * 2 + c] =                         \
                        __builtin_amdgcn_mfma_f32_16x16x32_bf16(              \
                            AF[r][s], BF[c][s],                               \
                            acc[(IH) * 4 + r][(JH) * 2 + c], 0, 0, 0);        \
                }                                                             \
            }                                                                 \
        }                                                                     \
    }

#define LDA_(AF, BUF, IH)                                                     \
    {                                                                         \
        const __hip_bfloat16* _ab = sm + (BUF) * 32768 + wm * 8192;           \
        _Pragma("unroll") for (int r = 0; r < 4; ++r) {                       \
            const int _row = (IH) * 64 + r * 16 + lr;                         \
            _Pragma("unroll") for (int s = 0; s < 2; ++s) {                   \
                AF[r][s] = *reinterpret_cast<const bf16x8*>(                  \
                    _ab + _row * 64 + (((s * 4 + kg) ^ (lr & 7)) * 8));       \
            }                                                                 \
        }                                                                     \
    }

#define LDB_(BF, BUF, JH)                                                     \
    {                                                                         \
        const __hip_bfloat16* _bb =                                           \
            sm + (BUF) * 32768 + (2 + (wn >> 1)) * 8192;                      \
        _Pragma("unroll") for (int c = 0; c < 2; ++c) {                       \
            const int _row = (wn & 1) * 64 + ((JH) * 2 + c) * 16 + lr;        \
            _Pragma("unroll") for (int s = 0; s < 2; ++s) {                   \
                BF[c][s] = *reinterpret_cast<const bf16x8*>(                  \
                    _bb + _row * 64 + (((s * 4 + kg) ^ (lr & 7)) * 8));       \
            }                                                                 \
        }                                                                     \
    }

#define SCHED __builtin_amdgcn_sched_barrier(0)
#define BAR __builtin_amdgcn_s_barrier()
#define PRIO1 __builtin_amdgcn_s_setprio(1)
#define PRIO0 __builtin_amdgcn_s_setprio(0)
#define VMC4 asm volatile("s_waitcnt vmcnt(4)" ::: "memory")
#define VMC0 asm volatile("s_waitcnt vmcnt(0)" ::: "memory")

template <int N, int K, int MODE>
__global__ __launch_bounds__(512, 1)
void gemm9p(const __hip_bfloat16* __restrict__ A,
            const __hip_bfloat16* __restrict__ Bw,
            const float* __restrict__ xq,
            __hip_bfloat16* __restrict__ out,
            const float* __restrict__ Gg, const float* __restrict__ Gb,
            const float* __restrict__ Gm, const float* __restrict__ Gv) {
    __shared__ __hip_bfloat16 sm[65536];   // 128 KB

    // XCD-aware block swizzle (nwg % 8 == 0 by launch config)
    const int nwg = gridDim.x;
    const int cpx = nwg >> 3;
    const int bid = blockIdx.x;
    const int orig = (bid & 7) * cpx + (bid >> 3);
    constexpr int NCB = N / 256;
    const int row0 = (orig / NCB) * 256;
    const int col0 = (orig % NCB) * 256;

    const int tid = threadIdx.x;
    const int lane = tid & 63;
    const int wv = tid >> 6;          // 0..7
    const int wm = wv >> 2, wn = wv & 3;
    const int lr = lane & 15, kg = lane >> 4;

    // staging source: thread tid covers (row_local = g*64 + tid/8,
    // chunk_pos = tid&7); source chunk = pos ^ (row&7) (pre-swizzled).
    const int schunk = (tid & 7) ^ ((tid >> 3) & 7);
    const __hip_bfloat16* srcA0 = A + (size_t)(row0 + (tid >> 3)) * K + schunk * 8;
    const __hip_bfloat16* srcB0 = Bw + (size_t)(col0 + (tid >> 3)) * K + schunk * 8;
    constexpr size_t H = (size_t)128 * K;   // +128 rows (second half-tile)

    auto STG = [&](int buf, int region, const __hip_bfloat16* src) {
        __hip_bfloat16* l = sm + buf * 32768 + region * 8192 + wv * 512;
        gload16(l, src);
        gload16(l + 4096, src + (size_t)64 * K);   // rows +64
    };

    f32x4 acc[8][4];
#pragma unroll
    for (int i = 0; i < 8; ++i)
#pragma unroll
        for (int j = 0; j < 4; ++j) acc[i][j] = (f32x4){0.f, 0.f, 0.f, 0.f};

    bf16x8 afA[4][2], afB[4][2], bL[2][2], bH[2][2];

    // ---- prologue: buf0 = tile0 (4 regions), buf1 = tile1 (B only) ----
    STG(0, 0, srcA0);          // A0(T0)
    STG(0, 1, srcA0 + H);      // A1(T0)
    STG(0, 2, srcB0);          // B0(T0)
    STG(0, 3, srcB0 + H);      // B1(T0)
    STG(1, 2, srcB0 + 64);     // B0(T1)
    STG(1, 3, srcB0 + H + 64); // B1(T1)
    VMC4;                      // buf0 landed (leaves buf1-B in flight)
    BAR;
    LDA_(afA, 0, 0);           // read-ahead for P1

    constexpr int niter = K / 128;
    for (int it = 0; it < niter; ++it) {
        const int k0 = it * 128;
        const bool pf = (it + 1 < niter);

        // ---- P1: MFMA Q(0,0) buf0 | rd bL(JIT)+bH(buf0-B) | stg A0(U+1)
        STG(1, 0, srcA0 + k0 + 64);
        LDB_(bL, 0, 0);
        LDB_(bH, 0, 1);
        SCHED; PRIO1; MMQ(afA, bL, 0, 0); PRIO0; SCHED; BAR;

        // ---- P2: MFMA Q(0,1) | rd afB(buf0-A ih1) | stg A1(U+1)
        STG(1, 1, srcA0 + H + k0 + 64);
        LDA_(afB, 0, 1);
        SCHED; PRIO1; MMQ(afA, bH, 0, 1); PRIO0; SCHED; BAR;

        // ---- P3: MFMA Q(1,1) | stg B0(U+2)
        if (pf) STG(0, 2, srcB0 + k0 + 128);
        SCHED; PRIO1; MMQ(afB, bH, 1, 1); PRIO0; SCHED; BAR;

        // ---- P4: publish buf1 | rd afA(buf1-A ih0) | MFMA Q(1,0) | stg B1
        if (pf) { STG(0, 3, srcB0 + H + k0 + 128); VMC4; } else { VMC0; }
        BAR;                                   // buf1 published block-wide
        LDA_(afA, 1, 0);
        SCHED; PRIO1; MMQ(afB, bL, 1, 0); PRIO0; SCHED; BAR;

        // ---- P5: MFMA Q(0,0) buf1 | rd bL'(JIT)+bH'(buf1-B) | stg A0(U+2)
        if (pf) STG(0, 0, srcA0 + k0 + 128);
        LDB_(bL, 1, 0);
        LDB_(bH, 1, 1);
        SCHED; PRIO1; MMQ(afA, bL, 0, 0); PRIO0; SCHED; BAR;

        // ---- P6: MFMA Q(0,1) | rd afB(buf1-A ih1) | stg A1(U+2)
        if (pf) STG(0, 1, srcA0 + H + k0 + 128);
        LDA_(afB, 1, 1);
        SCHED; PRIO1; MMQ(afA, bH, 0, 1); PRIO0; SCHED; BAR;

        // ---- P7: MFMA Q(1,1) | stg B0(U+3)
        if (pf) STG(1, 2, srcB0 + k0 + 192);
        SCHED; PRIO1; MMQ(afB, bH, 1, 1); PRIO0; SCHED; BAR;

        // ---- P8: publish buf0(U+2) | rd afA(next P1) | MFMA Q(1,0) | stg B1
        if (pf) { STG(1, 3, srcB0 + H + k0 + 192); VMC4; } else { VMC0; }
        BAR;                                   // buf0 published block-wide
        if (pf) LDA_(afA, 0, 0);
        SCHED; PRIO1; MMQ(afB, bL, 1, 0); PRIO0; SCHED; BAR;
    }

    // ---- epilogue: BN + LeakyReLU (+ xq for MODE 1), write-combined -------
    const int bq = row0 >> 11;  // batch index (tile rows within one batch)
    float scl[4], tcn[4], xqv[4];
#pragma unroll
    for (int j = 0; j < 4; ++j) {
        const int c = col0 + wn * 64 + j * 16 + lr;
        scl[j] = Gg[c] * rsqrtf(Gv[c] + 1e-5f);
        tcn[j] = Gb[c] - Gm[c] * scl[j];
        xqv[j] = (MODE == 1) ? xq[bq * 2048 + c] : 0.f;
    }
#pragma unroll
    for (int i = 0; i < 8; ++i) {
#pragma unroll
        for (int rI = 0; rI < 4; ++rI) {
            const int r = row0 + wm * 128 + i * 16 + kg * 4 + rI;
            const size_t rowoff = (size_t)r * N + col0 + wn * 64 + lr;
#pragma unroll
            for (int j = 0; j < 4; ++j) {
                float val = acc[i][j][rI] * scl[j] + tcn[j];
                val = LRELU(val) + xqv[j];
                out[rowoff + j * 16] = __float2bfloat16(val);
            }
        }
    }
}

// ---------------- GEMM3 (M x 64, K=512) fused with layer-4 + bn4 ----------
__global__ __launch_bounds__(256)
void gemm3_l4(const __hip_bfloat16* __restrict__ A,    // s2b [M,512]
              const __hip_bfloat16* __restrict__ W3b,  // [64,512]
              const float* __restrict__ W4,            // [64]
              const float* __restrict__ g3, const float* __restrict__ b3,
              const float* __restrict__ m3, const float* __restrict__ v3,
              const float* __restrict__ g4, const float* __restrict__ b4,
              const float* __restrict__ m4, const float* __restrict__ v4,
              float* __restrict__ logits) {
    const int lane = threadIdx.x & 63;
    const int wv = threadIdx.x >> 6;
    const int row0 = blockIdx.x * 128 + wv * 32;
    const int lr = lane & 15, kg = lane >> 4;

    f32x4 acc[2][4];
#pragma unroll
    for (int i = 0; i < 2; ++i)
#pragma unroll
        for (int j = 0; j < 4; ++j) acc[i][j] = (f32x4){0.f, 0.f, 0.f, 0.f};

    for (int k = 0; k < 512; k += 32) {
        const int kk = k + kg * 8;
        bf16x8 a[2], b[4];
#pragma unroll
        for (int i = 0; i < 2; ++i)
            a[i] = *reinterpret_cast<const bf16x8*>(A + (size_t)(row0 + i * 16 + lr) * 512 + kk);
#pragma unroll
        for (int j = 0; j < 4; ++j)
            b[j] = *reinterpret_cast<const bf16x8*>(W3b + (size_t)(j * 16 + lr) * 512 + kk);
#pragma unroll
        for (int i = 0; i < 2; ++i)
#pragma unroll
            for (int j = 0; j < 4; ++j)
                acc[i][j] = __builtin_amdgcn_mfma_f32_16x16x32_bf16(a[i], b[j], acc[i][j], 0, 0, 0);
    }

    const float sc4 = g4[0] * rsqrtf(v4[0] + 1e-5f);
    const float tc4 = b4[0] - m4[0] * sc4;
#pragma unroll
    for (int i = 0; i < 2; ++i) {
        float t[4] = {0.f, 0.f, 0.f, 0.f};
#pragma unroll
        for (int j = 0; j < 4; ++j) {
            const int c = j * 16 + lr;
            const float sc = g3[c] * rsqrtf(v3[c] + 1e-5f);
            const float tc = b3[c] - m3[c] * sc;
            const float w4c = W4[c];
#pragma unroll
            for (int rI = 0; rI < 4; ++rI) {
                float v = acc[i][j][rI] * sc + tc;
                t[rI] += LRELU(v) * w4c;
            }
        }
#pragma unroll
        for (int m = 1; m < 16; m <<= 1)
#pragma unroll
            for (int rI = 0; rI < 4; ++rI) t[rI] += __shfl_xor(t[rI], m, 64);
        if (lr == 0) {
#pragma unroll
            for (int rI = 0; rI < 4; ++rI) {
                float lg = t[rI] * sc4 + tc4;
                logits[row0 + i * 16 + kg * 4 + rI] = LRELU(lg);
            }
        }
    }
}

// ---------------- softmax over N=2048 per batch ----------------------------
__global__ void softmax2048(const float* __restrict__ logits, float* __restrict__ scores) {
    __shared__ float sh[2048];
    __shared__ float red[256];
    const int b = blockIdx.x, tid = threadIdx.x;
    float lmax = -1e30f;
#pragma unroll
    for (int it = 0; it < 8; ++it) {
        const int n = tid + it * 256;
        float v = logits[b * 2048 + n];
        sh[n] = v;
        lmax = fmaxf(lmax, v);
    }
    red[tid] = lmax;
    __syncthreads();
    for (int s = 128; s > 0; s >>= 1) {
        if (tid < s) red[tid] = fmaxf(red[tid], red[tid + s]);
        __syncthreads();
    }
    const float gmax = red[0];
    __syncthreads();
    float lsum = 0.f;
#pragma unroll
    for (int it = 0; it < 8; ++it) {
        const int n = tid + it * 256;
        float e = expf(sh[n] - gmax);
        sh[n] = e;
        lsum += e;
    }
    red[tid] = lsum;
    __syncthreads();
    for (int s = 128; s > 0; s >>= 1) {
        if (tid < s) red[tid] += red[tid + s];
        __syncthreads();
    }
    const float inv = 1.f / red[0];
#pragma unroll
    for (int it = 0; it < 8; ++it) {
        const int n = tid + it * 256;
        scores[b * 2048 + n] = sh[n] * inv;
    }
}

// ---------------- pooling over features, then subtract xq ------------------
// out[b,e] = sum_n features[b,n,e]*scores[b,n] - xq[b,e]   (sum scores = 1)
__global__ void pool_partial(const __hip_bfloat16* __restrict__ feats,
                             const float* __restrict__ scores,
                             float* __restrict__ partial) {
    const int b = blockIdx.y, nc = blockIdx.x;  // 32 chunks of 64 rows
    const int e0 = threadIdx.x * 8;
    float acc[8] = {0, 0, 0, 0, 0, 0, 0, 0};
    const size_t base = ((size_t)b * 2048 + nc * 64) * 2048;
    for (int i = 0; i < 64; ++i) {
        const float sc = scores[b * 2048 + nc * 64 + i];
        bf16x8 v = *reinterpret_cast<const bf16x8*>(feats + base + (size_t)i * 2048 + e0);
#pragma unroll
        for (int j = 0; j < 8; ++j) acc[j] += sc * (float)v[j];
    }
    float* p = partial + ((size_t)(b * 32 + nc)) * 2048 + e0;
#pragma unroll
    for (int j = 0; j < 8; ++j) p[j] = acc[j];
}

__global__ void pool_reduce(const float* __restrict__ partial,
                            const float* __restrict__ xq,
                            float* __restrict__ out) {
    const int i = blockIdx.x * blockDim.x + threadIdx.x;  // 0..32767
    const int b = i >> 11, e = i & 2047;
    float s = 0.f;
#pragma unroll
    for (int nc = 0; nc < 32; ++nc) s += partial[((size_t)(b * 32 + nc)) * 2048 + e];
    out[i] = s - xq[i];
}

// ---------------------------------------------------------------------------
extern "C" void kernel_launch(void* const* d_in, const int* in_sizes, int n_in,
                              void* d_out, int out_size, void* d_ws, size_t ws_size,
                              hipStream_t stream) {
    const float* xq = (const float*)d_in[0];
    const float* xk = (const float*)d_in[1];
    const float* W1 = (const float*)d_in[2];
    const float* W2 = (const float*)d_in[3];
    const float* W3 = (const float*)d_in[4];
    const float* W4 = (const float*)d_in[5];
    const float* g1 = (const float*)d_in[6], *b1 = (const float*)d_in[7];
    const float* m1 = (const float*)d_in[8], *v1 = (const float*)d_in[9];
    const float* g2 = (const float*)d_in[10], *b2 = (const float*)d_in[11];
    const float* m2 = (const float*)d_in[12], *v2 = (const float*)d_in[13];
    const float* g3 = (const float*)d_in[14], *b3 = (const float*)d_in[15];
    const float* m3 = (const float*)d_in[16], *v3 = (const float*)d_in[17];
    const float* g4 = (const float*)d_in[18], *b4 = (const float*)d_in[19];
    const float* m4 = (const float*)d_in[20], *v4 = (const float*)d_in[21];

    const int M = 32768;  // B*N = 16*2048

    char* ws = (char*)d_ws;
    size_t off = 0;
    auto alloc = [&](size_t bytes) {
        void* p = ws + off;
        off += (bytes + 255) & ~(size_t)255;
        return p;
    };
    __hip_bfloat16* xkb   = (__hip_bfloat16*)alloc((size_t)M * 512 * 2);
    __hip_bfloat16* w1b   = (__hip_bfloat16*)alloc((size_t)2048 * 512 * 2);
    __hip_bfloat16* w2b   = (__hip_bfloat16*)alloc((size_t)512 * 2048 * 2);
    __hip_bfloat16* w3b   = (__hip_bfloat16*)alloc((size_t)64 * 512 * 2);
    __hip_bfloat16* featb = (__hip_bfloat16*)alloc((size_t)M * 2048 * 2);
    __hip_bfloat16* s2b   = (__hip_bfloat16*)alloc((size_t)M * 512 * 2);
    float* logits         = (float*)alloc((size_t)M * 4);
    float* scores         = (float*)alloc((size_t)16 * 2048 * 4);
    float* partial        = (float*)alloc((size_t)16 * 32 * 2048 * 4);

    // converts
    cvt_f32_bf16<<<4096, 256, 0, stream>>>(xk, xkb, M * 512 / 4);
    cvt_f32_bf16<<<1024, 256, 0, stream>>>(W1, w1b, 2048 * 512 / 4);
    cvt_f32_bf16<<<1024, 256, 0, stream>>>(W2, w2b, 512 * 2048 / 4);
    cvt_f32_bf16<<<32, 256, 0, stream>>>(W3, w3b, 64 * 512 / 4);

    // GEMM1: features = lrelu(bn1(xk @ W1^T)) + xq   [M,2048] bf16
    gemm9p<2048, 512, 1><<<1024, 512, 0, stream>>>(
        xkb, w1b, xq, featb, g1, b1, m1, v1);

    // GEMM2: s2 = lrelu(bn2(features @ W2^T))        [M,512] bf16
    gemm9p<512, 2048, 2><<<256, 512, 0, stream>>>(
        featb, w2b, nullptr, s2b, g2, b2, m2, v2);

    // GEMM3 + layer4: logits [M] f32
    gemm3_l4<<<256, 256, 0, stream>>>(s2b, w3b, W4,
                                      g3, b3, m3, v3, g4, b4, m4, v4, logits);

    // softmax over N per batch
    softmax2048<<<16, 256, 0, stream>>>(logits, scores);

    // pooling (+ subtract xq)
    pool_partial<<<dim3(32, 16), 256, 0, stream>>>(featb, scores, partial);
    pool_reduce<<<128, 256, 0, stream>>>(partial, xq, (float*)d_out);
}

// Round 10
// 224.378 us; speedup vs baseline: 1.0579x; 1.0579x over previous
//
#include <hip/hip_runtime.h>
#include <hip/hip_bf16.h>

typedef __bf16 bf16x8 __attribute__((ext_vector_type(8)));
typedef float f32x4 __attribute__((ext_vector_type(4)));
typedef __attribute__((address_space(3))) void lds_void_t;
typedef __attribute__((address_space(1))) void gbl_void_t;

#define LRELU(x) ((x) >= 0.f ? (x) : 0.2f * (x))

__device__ __forceinline__ void gload16(void* lds_uniform, const void* gsrc) {
    __builtin_amdgcn_global_load_lds((const gbl_void_t*)gsrc, (lds_void_t*)lds_uniform,
                                     16, 0, 0);
}

__device__ __forceinline__ unsigned short f2u(float f) {
    __hip_bfloat16 h = __float2bfloat16(f);
    return reinterpret_cast<unsigned short&>(h);
}

// ---------------- fused f32 -> bf16 convert (4 tensors, one launch) --------
__global__ void cvt_fused(const float* __restrict__ a, __hip_bfloat16* __restrict__ oa, int na,
                          const float* __restrict__ b, __hip_bfloat16* __restrict__ ob, int nb,
                          const float* __restrict__ c, __hip_bfloat16* __restrict__ oc, int nc,
                          const float* __restrict__ d, __hip_bfloat16* __restrict__ od, int nd) {
    const int stride = gridDim.x * blockDim.x;
    const int total = na + nb + nc + nd;
    for (int i = blockIdx.x * blockDim.x + threadIdx.x; i < total; i += stride) {
        const float* s; __hip_bfloat16* o; int j = i;
        if (j < na) { s = a; o = oa; }
        else {
            j -= na;
            if (j < nb) { s = b; o = ob; }
            else {
                j -= nb;
                if (j < nc) { s = c; o = oc; }
                else { j -= nc; s = d; o = od; }
            }
        }
        float4 v = reinterpret_cast<const float4*>(s)[j];
        ushort4 u;
        u.x = f2u(v.x); u.y = f2u(v.y); u.z = f2u(v.z); u.w = f2u(v.w);
        reinterpret_cast<ushort4*>(o)[j] = u;
    }
}

// ============ 256x256 GEMM: 4-buffer rotation, depth-3 prefetch ============
// 8 waves (2M x 4N), per-wave C = 128x64 (acc[8][4] f32x4). BK=32 per tile,
// 2 template-phases per tile. LDS = 4 bufs x (A 8KB... A 16KB + B 16KB) =
// 4 x 32KB = 128 KB. Staging at iter t targets tile t+3 -> buf (t+3)&3,
// which is NEVER the buffer being read (3 apart, 4 bufs).
// Phase layout per iter t (tile t, buf b=t&3):
//  P1: [STAGE_A(t+3)] | ds_read af(ih0) 4 + bf 4 | bar | lgkm0 | 16 MFMA | bar
//  P2: [STAGE_B(t+3)] | ds_read af(ih1) 4 | vmcnt(8/4/0) | bar | lgkm0
//      | 16 MFMA | bar
// Ledger:
//  RAW: tile t+1 (read next-P1) staged at iter t-2; this iter's vmcnt(8)
//    allows only tiles t+2,t+3's 8 loads in flight => t+1 landed; barrier =>
//    block-wide. Stage-to-first-read age: 6-7 phases; vmcnt-wait age: 4-6.
//  WAR: stage at t targets buf holding tile t-1, whose ds_reads were
//    register-consumed at iter t-1's lgkm0 drains, >=2 barriers before the
//    stage issues.  WAW: each buf restaged every 4 tiles; older DMA drained.
//  Tail: t+3==niter -> vmcnt(4) (only t+2 in flight); t+2>=niter -> vmcnt(0).
// MODE 1: out = bf16(lrelu(bn(A@B^T)) + xq) ; MODE 2: out = bf16(lrelu(bn))
// ===========================================================================
template <int N, int K, int MODE>
__global__ __launch_bounds__(512, 1)
void gemm4b(const __hip_bfloat16* __restrict__ A,
            const __hip_bfloat16* __restrict__ Bw,
            const float* __restrict__ xq,
            __hip_bfloat16* __restrict__ out,
            const float* __restrict__ Gg, const float* __restrict__ Gb,
            const float* __restrict__ Gm, const float* __restrict__ Gv) {
    __shared__ __hip_bfloat16 sm[4 * 16384];   // 128 KB

    // XCD-aware block swizzle (nwg % 8 == 0 by launch config)
    const int nwg = gridDim.x;
    const int cpx = nwg >> 3;
    const int bid = blockIdx.x;
    const int orig = (bid & 7) * cpx + (bid >> 3);
    constexpr int NCB = N / 256;
    const int row0 = (orig / NCB) * 256;
    const int col0 = (orig % NCB) * 256;

    const int tid = threadIdx.x;
    const int lane = tid & 63;
    const int wv = tid >> 6;          // 0..7
    const int wm = wv >> 2, wn = wv & 3;
    const int lr = lane & 15, kg = lane >> 4;

    // ---- staging source (pre-swizzled global chunks; R6-proven) ----
    const int srow = tid >> 2;        // dest row (mod 128)
    const int sc = tid & 3;           // dest 16B-chunk position
    const int kch = ((sc ^ ((srow >> 1) & 3)) << 3);
    const __hip_bfloat16* As0 = A + (size_t)(row0 + srow) * K + kch;
    const __hip_bfloat16* As1 = A + (size_t)(row0 + 128 + srow) * K + kch;
    const __hip_bfloat16* Bs0 = Bw + (size_t)(col0 + srow) * K + kch;
    const __hip_bfloat16* Bs1 = Bw + (size_t)(col0 + 128 + srow) * K + kch;

    auto STAGE_A = [&](int b, int k0) {
        __hip_bfloat16* la = sm + b * 16384 + wv * 512;
        gload16(la,        As0 + k0);
        gload16(la + 4096, As1 + k0);
    };
    auto STAGE_B = [&](int b, int k0) {
        __hip_bfloat16* lb = sm + b * 16384 + 8192 + wv * 512;
        gload16(lb,        Bs0 + k0);
        gload16(lb + 4096, Bs1 + k0);
    };

    // ---- ds_read fragment offsets (swizzled chunk; R6-proven) ----
    const int f = (lr >> 1) & 3;
    const int koff = ((kg ^ f) << 3);
    const int aoff = (wm * 128 + lr) * 32 + koff;
    const int boff = 8192 + (wn * 64 + lr) * 32 + koff;

    f32x4 acc[8][4];
#pragma unroll
    for (int i = 0; i < 8; ++i)
#pragma unroll
        for (int j = 0; j < 4; ++j) acc[i][j] = (f32x4){0.f, 0.f, 0.f, 0.f};

    constexpr int niter = K / 32;
    // ---- prologue: stage tiles 0,1,2 ----
    STAGE_A(0, 0);  STAGE_B(0, 0);
    STAGE_A(1, 32); STAGE_B(1, 32);
    STAGE_A(2, 64); STAGE_B(2, 64);
    asm volatile("s_waitcnt vmcnt(8)" ::: "memory");   // tile 0 landed
    __builtin_amdgcn_s_barrier();

    for (int t = 0; t < niter; ++t) {
        const __hip_bfloat16* base = sm + (t & 3) * 16384;
        bf16x8 af[4], bf[4];

        // ================= P1 =================
        if (t + 3 < niter) STAGE_A((t + 3) & 3, (t + 3) * 32);
#pragma unroll
        for (int i = 0; i < 4; ++i)
            af[i] = *reinterpret_cast<const bf16x8*>(base + aoff + i * 512);
#pragma unroll
        for (int j = 0; j < 4; ++j)
            bf[j] = *reinterpret_cast<const bf16x8*>(base + boff + j * 512);
        __builtin_amdgcn_s_barrier();
        asm volatile("s_waitcnt lgkmcnt(0)" ::: "memory");
        __builtin_amdgcn_sched_barrier(0);
        __builtin_amdgcn_s_setprio(1);
#pragma unroll
        for (int i = 0; i < 4; ++i)
#pragma unroll
            for (int j = 0; j < 4; ++j)
                acc[i][j] = __builtin_amdgcn_mfma_f32_16x16x32_bf16(af[i], bf[j], acc[i][j], 0, 0, 0);
        __builtin_amdgcn_s_setprio(0);
        __builtin_amdgcn_sched_barrier(0);
        __builtin_amdgcn_s_barrier();

        // ================= P2 =================
        if (t + 3 < niter) {
            STAGE_B((t + 3) & 3, (t + 3) * 32);
            asm volatile("s_waitcnt vmcnt(8)" ::: "memory");  // tile t+1 landed
        } else if (t + 2 < niter) {
            asm volatile("s_waitcnt vmcnt(4)" ::: "memory");
        } else {
            asm volatile("s_waitcnt vmcnt(0)" ::: "memory");
        }
#pragma unroll
        for (int i = 0; i < 4; ++i)
            af[i] = *reinterpret_cast<const bf16x8*>(base + aoff + (4 + i) * 512);
        __builtin_amdgcn_s_barrier();
        asm volatile("s_waitcnt lgkmcnt(0)" ::: "memory");
        __builtin_amdgcn_sched_barrier(0);
        __builtin_amdgcn_s_setprio(1);
#pragma unroll
        for (int i = 0; i < 4; ++i)
#pragma unroll
            for (int j = 0; j < 4; ++j)
                acc[4 + i][j] = __builtin_amdgcn_mfma_f32_16x16x32_bf16(af[i], bf[j], acc[4 + i][j], 0, 0, 0);
        __builtin_amdgcn_s_setprio(0);
        __builtin_amdgcn_sched_barrier(0);
        __builtin_amdgcn_s_barrier();
    }

    // ---- epilogue: BN + LeakyReLU (+ xq for MODE 1) ----
    const int bq = row0 >> 11;  // batch index (tile rows within one batch)
    float scl[4], tcn[4], xqv[4];
#pragma unroll
    for (int j = 0; j < 4; ++j) {
        const int c = col0 + wn * 64 + j * 16 + lr;
        scl[j] = Gg[c] * rsqrtf(Gv[c] + 1e-5f);
        tcn[j] = Gb[c] - Gm[c] * scl[j];
        xqv[j] = (MODE == 1) ? xq[bq * 2048 + c] : 0.f;
    }
#pragma unroll
    for (int i = 0; i < 8; ++i) {
#pragma unroll
        for (int rI = 0; rI < 4; ++rI) {
            const int r = row0 + wm * 128 + i * 16 + kg * 4 + rI;
            const size_t rowoff = (size_t)r * N + col0 + wn * 64 + lr;
#pragma unroll
            for (int j = 0; j < 4; ++j) {
                float val = acc[i][j][rI] * scl[j] + tcn[j];
                val = LRELU(val) + xqv[j];
                out[rowoff + j * 16] = __float2bfloat16(val);
            }
        }
    }
}

// ---------------- GEMM3 (M x 64, K=512) fused with layer-4 + bn4 ----------
__global__ __launch_bounds__(256)
void gemm3_l4(const __hip_bfloat16* __restrict__ A,    // s2b [M,512]
              const __hip_bfloat16* __restrict__ W3b,  // [64,512]
              const float* __restrict__ W4,            // [64]
              const float* __restrict__ g3, const float* __restrict__ b3,
              const float* __restrict__ m3, const float* __restrict__ v3,
              const float* __restrict__ g4, const float* __restrict__ b4,
              const float* __restrict__ m4, const float* __restrict__ v4,
              float* __restrict__ logits) {
    const int lane = threadIdx.x & 63;
    const int wv = threadIdx.x >> 6;
    const int row0 = blockIdx.x * 128 + wv * 32;
    const int lr = lane & 15, kg = lane >> 4;

    f32x4 acc[2][4];
#pragma unroll
    for (int i = 0; i < 2; ++i)
#pragma unroll
        for (int j = 0; j < 4; ++j) acc[i][j] = (f32x4){0.f, 0.f, 0.f, 0.f};

    for (int k = 0; k < 512; k += 32) {
        const int kk = k + kg * 8;
        bf16x8 a[2], b[4];
#pragma unroll
        for (int i = 0; i < 2; ++i)
            a[i] = *reinterpret_cast<const bf16x8*>(A + (size_t)(row0 + i * 16 + lr) * 512 + kk);
#pragma unroll
        for (int j = 0; j < 4; ++j)
            b[j] = *reinterpret_cast<const bf16x8*>(W3b + (size_t)(j * 16 + lr) * 512 + kk);
#pragma unroll
        for (int i = 0; i < 2; ++i)
#pragma unroll
            for (int j = 0; j < 4; ++j)
                acc[i][j] = __builtin_amdgcn_mfma_f32_16x16x32_bf16(a[i], b[j], acc[i][j], 0, 0, 0);
    }

    const float sc4 = g4[0] * rsqrtf(v4[0] + 1e-5f);
    const float tc4 = b4[0] - m4[0] * sc4;
#pragma unroll
    for (int i = 0; i < 2; ++i) {
        float t[4] = {0.f, 0.f, 0.f, 0.f};
#pragma unroll
        for (int j = 0; j < 4; ++j) {
            const int c = j * 16 + lr;
            const float sc = g3[c] * rsqrtf(v3[c] + 1e-5f);
            const float tc = b3[c] - m3[c] * sc;
            const float w4c = W4[c];
#pragma unroll
            for (int rI = 0; rI < 4; ++rI) {
                float v = acc[i][j][rI] * sc + tc;
                t[rI] += LRELU(v) * w4c;
            }
        }
#pragma unroll
        for (int m = 1; m < 16; m <<= 1)
#pragma unroll
            for (int rI = 0; rI < 4; ++rI) t[rI] += __shfl_xor(t[rI], m, 64);
        if (lr == 0) {
#pragma unroll
            for (int rI = 0; rI < 4; ++rI) {
                float lg = t[rI] * sc4 + tc4;
                logits[row0 + i * 16 + kg * 4 + rI] = LRELU(lg);
            }
        }
    }
}

// ---------------- softmax over N=2048 per batch ----------------------------
__global__ void softmax2048(const float* __restrict__ logits, float* __restrict__ scores) {
    __shared__ float sh[2048];
    __shared__ float red[256];
    const int b = blockIdx.x, tid = threadIdx.x;
    float lmax = -1e30f;
#pragma unroll
    for (int it = 0; it < 8; ++it) {
        const int n = tid + it * 256;
        float v = logits[b * 2048 + n];
        sh[n] = v;
        lmax = fmaxf(lmax, v);
    }
    red[tid] = lmax;
    __syncthreads();
    for (int s = 128; s > 0; s >>= 1) {
        if (tid < s) red[tid] = fmaxf(red[tid], red[tid + s]);
        __syncthreads();
    }
    const float gmax = red[0];
    __syncthreads();
    float lsum = 0.f;
#pragma unroll
    for (int it = 0; it < 8; ++it) {
        const int n = tid + it * 256;
        float e = expf(sh[n] - gmax);
        sh[n] = e;
        lsum += e;
    }
    red[tid] = lsum;
    __syncthreads();
    for (int s = 128; s > 0; s >>= 1) {
        if (tid < s) red[tid] += red[tid + s];
        __syncthreads();
    }
    const float inv = 1.f / red[0];
#pragma unroll
    for (int it = 0; it < 8; ++it) {
        const int n = tid + it * 256;
        scores[b * 2048 + n] = sh[n] * inv;
    }
}

// ---------------- pooling over features, then subtract xq ------------------
// out[b,e] = sum_n features[b,n,e]*scores[b,n] - xq[b,e]   (sum scores = 1)
__global__ void pool_partial(const __hip_bfloat16* __restrict__ feats,
                             const float* __restrict__ scores,
                             float* __restrict__ partial) {
    const int b = blockIdx.y, nc = blockIdx.x;  // 32 chunks of 64 rows
    const int e0 = threadIdx.x * 8;
    float acc[8] = {0, 0, 0, 0, 0, 0, 0, 0};
    const size_t base = ((size_t)b * 2048 + nc * 64) * 2048;
    for (int i = 0; i < 64; ++i) {
        const float sc = scores[b * 2048 + nc * 64 + i];
        bf16x8 v = *reinterpret_cast<const bf16x8*>(feats + base + (size_t)i * 2048 + e0);
#pragma unroll
        for (int j = 0; j < 8; ++j) acc[j] += sc * (float)v[j];
    }
    float* p = partial + ((size_t)(b * 32 + nc)) * 2048 + e0;
#pragma unroll
    for (int j = 0; j < 8; ++j) p[j] = acc[j];
}

__global__ void pool_reduce(const float* __restrict__ partial,
                            const float* __restrict__ xq,
                            float* __restrict__ out) {
    const int i = blockIdx.x * blockDim.x + threadIdx.x;  // 0..32767
    const int b = i >> 11, e = i & 2047;
    float s = 0.f;
#pragma unroll
    for (int nc = 0; nc < 32; ++nc) s += partial[((size_t)(b * 32 + nc)) * 2048 + e];
    out[i] = s - xq[i];
}

// ---------------------------------------------------------------------------
extern "C" void kernel_launch(void* const* d_in, const int* in_sizes, int n_in,
                              void* d_out, int out_size, void* d_ws, size_t ws_size,
                              hipStream_t stream) {
    const float* xq = (const float*)d_in[0];
    const float* xk = (const float*)d_in[1];
    const float* W1 = (const float*)d_in[2];
    const float* W2 = (const float*)d_in[3];
    const float* W3 = (const float*)d_in[4];
    const float* W4 = (const float*)d_in[5];
    const float* g1 = (const float*)d_in[6], *b1 = (const float*)d_in[7];
    const float* m1 = (const float*)d_in[8], *v1 = (const float*)d_in[9];
    const float* g2 = (const float*)d_in[10], *b2 = (const float*)d_in[11];
    const float* m2 = (const float*)d_in[12], *v2 = (const float*)d_in[13];
    const float* g3 = (const float*)d_in[14], *b3 = (const float*)d_in[15];
    const float* m3 = (const float*)d_in[16], *v3 = (const float*)d_in[17];
    const float* g4 = (const float*)d_in[18], *b4 = (const float*)d_in[19];
    const float* m4 = (const float*)d_in[20], *v4 = (const float*)d_in[21];

    const int M = 32768;  // B*N = 16*2048

    char* ws = (char*)d_ws;
    size_t off = 0;
    auto alloc = [&](size_t bytes) {
        void* p = ws + off;
        off += (bytes + 255) & ~(size_t)255;
        return p;
    };
    __hip_bfloat16* xkb   = (__hip_bfloat16*)alloc((size_t)M * 512 * 2);
    __hip_bfloat16* w1b   = (__hip_bfloat16*)alloc((size_t)2048 * 512 * 2);
    __hip_bfloat16* w2b   = (__hip_bfloat16*)alloc((size_t)512 * 2048 * 2);
    __hip_bfloat16* w3b   = (__hip_bfloat16*)alloc((size_t)64 * 512 * 2);
    __hip_bfloat16* featb = (__hip_bfloat16*)alloc((size_t)M * 2048 * 2);
    __hip_bfloat16* s2b   = (__hip_bfloat16*)alloc((size_t)M * 512 * 2);
    float* logits         = (float*)alloc((size_t)M * 4);
    float* scores         = (float*)alloc((size_t)16 * 2048 * 4);
    float* partial        = (float*)alloc((size_t)16 * 32 * 2048 * 4);

    // fused converts (one launch)
    cvt_fused<<<4096, 256, 0, stream>>>(
        xk, xkb, M * 512 / 4,
        W1, w1b, 2048 * 512 / 4,
        W2, w2b, 512 * 2048 / 4,
        W3, w3b, 64 * 512 / 4);

    // GEMM1: features = lrelu(bn1(xk @ W1^T)) + xq   [M,2048] bf16
    gemm4b<2048, 512, 1><<<1024, 512, 0, stream>>>(
        xkb, w1b, xq, featb, g1, b1, m1, v1);

    // GEMM2: s2 = lrelu(bn2(features @ W2^T))        [M,512] bf16
    gemm4b<512, 2048, 2><<<256, 512, 0, stream>>>(
        featb, w2b, nullptr, s2b, g2, b2, m2, v2);

    // GEMM3 + layer4: logits [M] f32
    gemm3_l4<<<256, 256, 0, stream>>>(s2b, w3b, W4,
                                      g3, b3, m3, v3, g4, b4, m4, v4, logits);

    // softmax over N per batch
    softmax2048<<<16, 256, 0, stream>>>(logits, scores);

    // pooling (+ subtract xq)
    pool_partial<<<dim3(32, 16), 256, 0, stream>>>(featb, scores, partial);
    pool_reduce<<<128, 256, 0, stream>>>(partial, xq, (float*)d_out);
}